// Round 1
// baseline (346.468 us; speedup 1.0000x reference)
//
#include <hip/hip_runtime.h>

#define NUM_INST 64
#define ASLOT 11   // LDS accumulator stride in floats: gcd(11,32)=1 -> 64 label bases spread over all 32 banks
#define BLOCK 256
#define GRID 1024

__global__ __launch_bounds__(BLOCK) void vsl_main(const float4* __restrict__ rows,
                                                  const int* __restrict__ labels,
                                                  float* __restrict__ gacc, int n) {
    // one shared accumulator per block: 64 labels x {8 sums, ssq, count}, stride 11
    __shared__ float acc[NUM_INST * ASLOT];
    for (int j = threadIdx.x; j < NUM_INST * ASLOT; j += BLOCK) acc[j] = 0.0f;
    __syncthreads();

    const int stride = GRID * BLOCK;
    for (int i = blockIdx.x * BLOCK + threadIdx.x; i < n; i += stride) {
        const int lbl = labels[i];
        const float4 a = rows[2 * i];      // wave reads 2 KiB contiguous -> fully coalesced
        const float4 b = rows[2 * i + 1];

        float ssq = a.x * a.x;
        ssq = fmaf(a.y, a.y, ssq);
        ssq = fmaf(a.z, a.z, ssq);
        ssq = fmaf(a.w, a.w, ssq);
        ssq = fmaf(b.x, b.x, ssq);
        ssq = fmaf(b.y, b.y, ssq);
        ssq = fmaf(b.z, b.z, ssq);
        ssq = fmaf(b.w, b.w, ssq);

        // 10 ds_add_f32 off one base register (offsets 0..36 fold into the DS immediate)
        float* s = &acc[lbl * ASLOT];
        atomicAdd(&s[0], a.x);
        atomicAdd(&s[1], a.y);
        atomicAdd(&s[2], a.z);
        atomicAdd(&s[3], a.w);
        atomicAdd(&s[4], b.x);
        atomicAdd(&s[5], b.y);
        atomicAdd(&s[6], b.z);
        atomicAdd(&s[7], b.w);
        atomicAdd(&s[8], ssq);
        atomicAdd(&s[9], 1.0f);
    }
    __syncthreads();

    // one global atomic per (label, stat) per block -> gacc laid out [64][10]
    for (int j = threadIdx.x; j < NUM_INST * 10; j += BLOCK) {
        const int lbl = j / 10;
        const int st = j - lbl * 10;
        atomicAdd(&gacc[j], acc[lbl * ASLOT + st]);
    }
}

__global__ __launch_bounds__(64) void vsl_final(const float* __restrict__ gacc,
                                                float* __restrict__ out) {
    const int s = threadIdx.x;  // one thread per instance, 1 wave
    float val = 0.0f;
    const float* base = &gacc[s * 10];
    const float cnt = base[9];
    if (s != 0 && cnt > 0.0f) {
        const float ss = base[8];
        float m2 = 0.0f;
#pragma unroll
        for (int d = 0; d < 8; ++d) {
            const float sd = base[d];
            m2 += sd * sd;
        }
        val = (ss - m2 / cnt) / (cnt * 8.0f);
    }
#pragma unroll
    for (int off = 32; off > 0; off >>= 1) val += __shfl_down(val, off, 64);
    if (s == 0) out[0] = val;
}

extern "C" void kernel_launch(void* const* d_in, const int* in_sizes, int n_in,
                              void* d_out, int out_size, void* d_ws, size_t ws_size,
                              hipStream_t stream) {
    const float* variances = (const float*)d_in[0];  // [N, 8] fp32
    const int* labels = (const int*)d_in[1];         // [N] int32
    const int n = in_sizes[1];                       // N
    float* gacc = (float*)d_ws;                      // 640 floats of scratch

    hipMemsetAsync(d_ws, 0, NUM_INST * 10 * sizeof(float), stream);
    vsl_main<<<GRID, BLOCK, 0, stream>>>((const float4*)variances, labels, gacc, n);
    vsl_final<<<1, 64, 0, stream>>>(gacc, (float*)d_out);
}

// Round 2
// 227.643 us; speedup vs baseline: 1.5220x; 1.5220x over previous
//
#include <hip/hip_runtime.h>

#define NUM_INST 64
#define SLOT 12      // floats per routing slot: 9 used (a,b,ssq); 48B stride keeps 16B align, period-8 banks
#define BLOCK 256
#define NWAVES 4
#define GRID 2048    // 8 blocks/CU -> 32 waves/CU: hide LDS+L3 latency with TLP

__global__ __launch_bounds__(BLOCK) void vsl_main(const float4* __restrict__ rows,
                                                  const int* __restrict__ labels,
                                                  float* __restrict__ gacc, int n) {
    // per-wave private routing buffer: no cross-wave sharing -> no barriers in the loop
    __shared__ float lds[NWAVES][NUM_INST * SLOT];
    const int tid = threadIdx.x;
    const int w = tid >> 6;
    const int lane = tid & 63;

    // lane d of each wave owns label d
    float s0 = 0, s1 = 0, s2 = 0, s3 = 0, s4 = 0, s5 = 0, s6 = 0, s7 = 0;
    float ssq = 0, cntf = 0;

    float* slotbase = &lds[w][lane * SLOT];
    const int stride = GRID * BLOCK;

    // ---- prologue: load chunk 0 ----
    int i = blockIdx.x * BLOCK + tid;
    bool valid = (i < n);
    unsigned long long bv = __ballot(valid);
    int lbl = 0;
    float4 a = {0, 0, 0, 0}, b = {0, 0, 0, 0};
    if (valid) {
        lbl = labels[i];
        a = rows[2 * i];
        b = rows[2 * i + 1];
    }

    while (bv) {
        // ---- prefetch chunk t+1 early: its ~200cy L3 latency hides under this gather ----
        const int inext = i + stride;
        const bool vnext = (inext < n);
        const unsigned long long bvn = __ballot(vnext);
        int lbln = 0;
        float4 an = {0, 0, 0, 0}, bn = {0, 0, 0, 0};
        if (vnext) {
            lbln = labels[inext];
            an = rows[2 * inext];
            bn = rows[2 * inext + 1];
        }

        // source-side ssq (parallel over 64 lanes) so the serialized gather does 9 adds,
        // not 8 adds + 8 FMAs
        float sq = a.x * a.x;
        sq = fmaf(a.y, a.y, sq); sq = fmaf(a.z, a.z, sq); sq = fmaf(a.w, a.w, sq);
        sq = fmaf(b.x, b.x, sq); sq = fmaf(b.y, b.y, sq);
        sq = fmaf(b.z, b.z, sq); sq = fmaf(b.w, b.w, sq);

        // publish to my private slot (same-wave DS is in-order; lds[] may-alias keeps
        // the compiler from sinking these below the gather reads)
        *(float4*)(slotbase) = a;
        *(float4*)(slotbase + 4) = b;
        slotbase[8] = sq;

        // 6 ballots on label bits -> mask of source lanes whose label == my lane id
        unsigned long long m = bv;
#pragma unroll
        for (int bpos = 0; bpos < 6; ++bpos) {
            const unsigned long long bb = __ballot((lbl >> bpos) & 1);
            m &= ((lane >> bpos) & 1) ? bb : ~bb;
        }
        cntf += (float)__popcll(m);  // exact integer counts, no atomic

        // ---- 2-deep software-pipelined gather: issue bucket k+1's reads before
        //      accumulating bucket k, so each serial step pays issue cost not latency ----
        int g = -1;
        float4 p = {0, 0, 0, 0}, q = {0, 0, 0, 0};
        float r = 0;
        if (m) {
            g = (int)__builtin_ctzll(m);
            m &= m - 1;
            const float* sp = &lds[w][g * SLOT];
            p = *(const float4*)sp;
            q = *(const float4*)(sp + 4);
            r = sp[8];
        }
        while (g >= 0) {
            int g2 = -1;
            float4 p2 = {0, 0, 0, 0}, q2 = {0, 0, 0, 0};
            float r2 = 0;
            if (m) {
                g2 = (int)__builtin_ctzll(m);
                m &= m - 1;
                const float* sp = &lds[w][g2 * SLOT];
                p2 = *(const float4*)sp;
                q2 = *(const float4*)(sp + 4);
                r2 = sp[8];
            }
            s0 += p.x; s1 += p.y; s2 += p.z; s3 += p.w;
            s4 += q.x; s5 += q.y; s6 += q.z; s7 += q.w;
            ssq += r;
            g = g2; p = p2; q = q2; r = r2;
        }

        // rotate prefetched chunk in
        i = inext; bv = bvn; lbl = lbln; a = an; b = bn;
    }

    // flush: reuse the routing buffer for the per-wave totals (own region, own wave -> safe)
    float* fb = &lds[w][lane * SLOT];
    fb[0] = s0; fb[1] = s1; fb[2] = s2; fb[3] = s3;
    fb[4] = s4; fb[5] = s5; fb[6] = s6; fb[7] = s7;
    fb[8] = ssq; fb[9] = cntf;
    __syncthreads();

    // cross-wave reduce + one global atomic per (label, stat) per block
    for (int j = tid; j < NUM_INST * 10; j += BLOCK) {
        const int lbl2 = j / 10;
        const int st = j - lbl2 * 10;
        float v = 0;
#pragma unroll
        for (int ww = 0; ww < NWAVES; ++ww) v += lds[ww][lbl2 * SLOT + st];
        atomicAdd(&gacc[j], v);
    }
}

__global__ __launch_bounds__(64) void vsl_final(const float* __restrict__ gacc,
                                                float* __restrict__ out) {
    const int s = threadIdx.x;  // one thread per instance, 1 wave
    float val = 0.0f;
    const float* base = &gacc[s * 10];
    const float cnt = base[9];
    if (s != 0 && cnt > 0.0f) {
        const float ss = base[8];
        float m2 = 0.0f;
#pragma unroll
        for (int d = 0; d < 8; ++d) {
            const float sd = base[d];
            m2 += sd * sd;
        }
        val = (ss - m2 / cnt) / (cnt * 8.0f);
    }
#pragma unroll
    for (int off = 32; off > 0; off >>= 1) val += __shfl_down(val, off, 64);
    if (s == 0) out[0] = val;
}

extern "C" void kernel_launch(void* const* d_in, const int* in_sizes, int n_in,
                              void* d_out, int out_size, void* d_ws, size_t ws_size,
                              hipStream_t stream) {
    const float* variances = (const float*)d_in[0];  // [N, 8] fp32
    const int* labels = (const int*)d_in[1];         // [N] int32
    const int n = in_sizes[1];                       // N
    float* gacc = (float*)d_ws;                      // 640 floats of scratch

    hipMemsetAsync(d_ws, 0, NUM_INST * 10 * sizeof(float), stream);
    vsl_main<<<GRID, BLOCK, 0, stream>>>((const float4*)variances, labels, gacc, n);
    vsl_final<<<1, 64, 0, stream>>>(gacc, (float*)d_out);
}

// Round 3
// 212.409 us; speedup vs baseline: 1.6311x; 1.0717x over previous
//
#include <hip/hip_runtime.h>

#define NUM_INST 64
#define SLOT 12      // floats per routing slot: 9 used (a,b,ssq); 48B stride keeps 16B align, period-8 banks
#define BLOCK 256
#define NWAVES 4
#define GRID 1536    // 6 blocks/CU; LDS 24KB/block -> 147KB/CU -> 24 waves/CU (75%)
#define RCH 2        // chunks batched per routing phase: 6 VMEM in flight, merged gather

__global__ __launch_bounds__(BLOCK) void vsl_main(const float4* __restrict__ rows,
                                                  const int* __restrict__ labels,
                                                  float* __restrict__ gacc, int n) {
    // per-wave private routing buffer: [RCH*64 slots][12 floats]; no cross-wave sharing -> no barriers
    __shared__ float lds[NWAVES][RCH * NUM_INST * SLOT];
    const int tid = threadIdx.x;
    const int w = tid >> 6;
    const int lane = tid & 63;

    // lane d of each wave owns label d
    float s0 = 0, s1 = 0, s2 = 0, s3 = 0, s4 = 0, s5 = 0, s6 = 0, s7 = 0;
    float ssq = 0, cntf = 0;

    const int S = GRID * BLOCK;
    const int phaseStride = RCH * S;
    const int nphases = (n + phaseStride - 1) / phaseStride;  // uniform across all threads

    float* slot0 = &lds[w][lane * SLOT];
    float* slot1 = &lds[w][(NUM_INST + lane) * SLOT];

    int i0 = blockIdx.x * BLOCK + tid;

    for (int ph = 0; ph < nphases; ++ph, i0 += phaseStride) {
        const int i1 = i0 + S;
        const bool v0 = (i0 < n);
        const bool v1 = (i1 < n);

        // ---- issue ALL global loads for the phase back-to-back (6 VMEM, ~4.5KB in flight) ----
        int l0 = 0, l1 = 0;
        float4 a0 = {0, 0, 0, 0}, b0 = {0, 0, 0, 0};
        float4 a1 = {0, 0, 0, 0}, b1 = {0, 0, 0, 0};
        if (v0) { l0 = labels[i0]; a0 = rows[2 * i0]; b0 = rows[2 * i0 + 1]; }
        if (v1) { l1 = labels[i1]; a1 = rows[2 * i1]; b1 = rows[2 * i1 + 1]; }

        // source-side ssq (parallel over 64 lanes): gather step does 9 adds, not 8 adds + 8 FMAs
        float q0 = a0.x * a0.x;
        q0 = fmaf(a0.y, a0.y, q0); q0 = fmaf(a0.z, a0.z, q0); q0 = fmaf(a0.w, a0.w, q0);
        q0 = fmaf(b0.x, b0.x, q0); q0 = fmaf(b0.y, b0.y, q0);
        q0 = fmaf(b0.z, b0.z, q0); q0 = fmaf(b0.w, b0.w, q0);
        float q1 = a1.x * a1.x;
        q1 = fmaf(a1.y, a1.y, q1); q1 = fmaf(a1.z, a1.z, q1); q1 = fmaf(a1.w, a1.w, q1);
        q1 = fmaf(b1.x, b1.x, q1); q1 = fmaf(b1.y, b1.y, q1);
        q1 = fmaf(b1.z, b1.z, q1); q1 = fmaf(b1.w, b1.w, q1);

        // publish both rows to my private slots (same-wave DS is in-order)
        *(float4*)(slot0) = a0;
        *(float4*)(slot0 + 4) = b0;
        slot0[8] = q0;
        *(float4*)(slot1) = a1;
        *(float4*)(slot1 + 4) = b1;
        slot1[8] = q1;

        // 6 ballots per chunk on label bits -> per-lane source masks
        const unsigned long long bv0 = __ballot(v0);
        const unsigned long long bv1 = __ballot(v1);
        unsigned long long m0 = bv0, m1 = bv1;
#pragma unroll
        for (int bpos = 0; bpos < 6; ++bpos) {
            const unsigned long long t0 = __ballot((l0 >> bpos) & 1);
            const unsigned long long t1 = __ballot((l1 >> bpos) & 1);
            const bool mybit = (lane >> bpos) & 1;
            m0 &= mybit ? t0 : ~t0;
            m1 &= mybit ? t1 : ~t1;
        }
        cntf += (float)(__popcll(m0) + __popcll(m1));  // exact integer counts, no atomic

        // writes visible before gathering (same-wave DS in-order; clobber stops reordering)
        asm volatile("s_waitcnt lgkmcnt(0)" ::: "memory");

        // ---- merged gather over both chunks: wave serializes on max TOTAL bucket
        //      (Poisson(2) max ~6-7 for 128 rows) instead of 2x max(Poisson(1)) ~10 ----
        while (m0 | m1) {
            const bool use0 = (m0 != 0);
            unsigned long long mc = use0 ? m0 : m1;
            const int s = (int)__builtin_ctzll(mc);
            mc &= mc - 1;
            if (use0) m0 = mc; else m1 = mc;
            const float* sp = &lds[w][((use0 ? 0 : NUM_INST) + s) * SLOT];
            const float4 p = *(const float4*)sp;
            const float4 q = *(const float4*)(sp + 4);
            const float r = sp[8];
            s0 += p.x; s1 += p.y; s2 += p.z; s3 += p.w;
            s4 += q.x; s5 += q.y; s6 += q.z; s7 += q.w;
            ssq += r;
        }
    }

    // flush: reuse the routing buffer for the per-wave totals (own region, own wave -> safe)
    float* fb = &lds[w][lane * SLOT];
    fb[0] = s0; fb[1] = s1; fb[2] = s2; fb[3] = s3;
    fb[4] = s4; fb[5] = s5; fb[6] = s6; fb[7] = s7;
    fb[8] = ssq; fb[9] = cntf;
    __syncthreads();

    // cross-wave reduce + one global atomic per (label, stat) per block
    for (int j = tid; j < NUM_INST * 10; j += BLOCK) {
        const int lbl2 = j / 10;
        const int st = j - lbl2 * 10;
        float v = 0;
#pragma unroll
        for (int ww = 0; ww < NWAVES; ++ww) v += lds[ww][lbl2 * SLOT + st];
        atomicAdd(&gacc[j], v);
    }
}

__global__ __launch_bounds__(64) void vsl_final(const float* __restrict__ gacc,
                                                float* __restrict__ out) {
    const int s = threadIdx.x;  // one thread per instance, 1 wave
    float val = 0.0f;
    const float* base = &gacc[s * 10];
    const float cnt = base[9];
    if (s != 0 && cnt > 0.0f) {
        const float ss = base[8];
        float m2 = 0.0f;
#pragma unroll
        for (int d = 0; d < 8; ++d) {
            const float sd = base[d];
            m2 += sd * sd;
        }
        val = (ss - m2 / cnt) / (cnt * 8.0f);
    }
#pragma unroll
    for (int off = 32; off > 0; off >>= 1) val += __shfl_down(val, off, 64);
    if (s == 0) out[0] = val;
}

extern "C" void kernel_launch(void* const* d_in, const int* in_sizes, int n_in,
                              void* d_out, int out_size, void* d_ws, size_t ws_size,
                              hipStream_t stream) {
    const float* variances = (const float*)d_in[0];  // [N, 8] fp32
    const int* labels = (const int*)d_in[1];         // [N] int32
    const int n = in_sizes[1];                       // N
    float* gacc = (float*)d_ws;                      // 640 floats of scratch

    hipMemsetAsync(d_ws, 0, NUM_INST * 10 * sizeof(float), stream);
    vsl_main<<<GRID, BLOCK, 0, stream>>>((const float4*)variances, labels, gacc, n);
    vsl_final<<<1, 64, 0, stream>>>(gacc, (float*)d_out);
}